// Round 2
// baseline (719.322 us; speedup 1.0000x reference)
//
#include <hip/hip_runtime.h>
#include <cstdint>

// ---------------------------------------------------------------------------
// 2-layer GCN via on-device CSR build + per-node gather (no atomics in the
// hot aggregation loops).
//
//   hist:    cnt[c] += 1 ; deg[c] += ew        (atomics, small 400KB targets)
//   scan:    ptr = exclusive_scan(cnt)         (3 tiny kernels)
//   reorder: pos = fill[c]++ ; rw[pos] = (row, ew)
//   dis_xw1: dis = rsqrt(deg+1); xs1 = (x @ W1^T) * dis          [N,32]
//   gather1: h = relu(dis[i]*(sum_e w*xs1[r] + xs1[i]) + b1)     [N,32]
//   epi1:    xs2 = (h @ W2^T) * dis                              [N,16]
//   gather2: out = dis[i]*(sum_e w*xs2[r] + xs2[i]) + b2         [N,16]
// ---------------------------------------------------------------------------

__global__ void hist_kernel(const int* __restrict__ col,
                            const float* __restrict__ ew,
                            int* __restrict__ cnt,
                            float* __restrict__ deg, int E) {
    int e = blockIdx.x * blockDim.x + threadIdx.x;
    if (e < E) {
        int c = col[e];
        atomicAdd(&cnt[c], 1);
        atomicAdd(&deg[c], ew[e]);
    }
}

// exclusive scan, 256 elems/block
__global__ void scan1_kernel(const int* __restrict__ cnt, int* __restrict__ excl,
                             int* __restrict__ bsum, int N) {
    __shared__ int s[256];
    int tid = threadIdx.x;
    int i = blockIdx.x * 256 + tid;
    int v = (i < N) ? cnt[i] : 0;
    s[tid] = v;
    __syncthreads();
    for (int off = 1; off < 256; off <<= 1) {
        int t = (tid >= off) ? s[tid - off] : 0;
        __syncthreads();
        s[tid] += t;
        __syncthreads();
    }
    if (i < N) excl[i] = s[tid] - v;
    if (tid == 255) bsum[blockIdx.x] = s[255];
}

__global__ void scan2_kernel(int* __restrict__ bsum, int nb) {
    __shared__ int s[512];
    int tid = threadIdx.x;
    int v = (tid < nb) ? bsum[tid] : 0;
    s[tid] = v;
    __syncthreads();
    for (int off = 1; off < 512; off <<= 1) {
        int t = (tid >= off) ? s[tid - off] : 0;
        __syncthreads();
        s[tid] += t;
        __syncthreads();
    }
    if (tid < nb) bsum[tid] = s[tid] - v;  // exclusive block offsets
}

__global__ void scan3_kernel(int* __restrict__ excl, const int* __restrict__ bsum,
                             int* __restrict__ fill, int N, int E) {
    int i = blockIdx.x * 256 + threadIdx.x;
    if (i < N) {
        int p = excl[i] + bsum[i >> 8];
        excl[i] = p;
        fill[i] = p;
    } else if (i == N) {
        excl[N] = E;
    }
}

__global__ void reorder_kernel(const int* __restrict__ row, const int* __restrict__ col,
                               const float* __restrict__ ew,
                               int* __restrict__ fill, int2* __restrict__ rw, int E) {
    int e = blockIdx.x * blockDim.x + threadIdx.x;
    if (e >= E) return;
    int c = col[e];
    int pos = atomicAdd(&fill[c], 1);
    int2 v;
    v.x = row[e];
    v.y = __float_as_int(ew[e]);
    rw[pos] = v;
}

// dis = rsqrt(deg+1); xs1 = (x @ W1^T) * dis   (W1: [32,16] row-major)
__global__ void dis_xw1_kernel(const float* __restrict__ x,
                               const float* __restrict__ W1,
                               const float* __restrict__ deg,
                               float* __restrict__ dis,
                               float* __restrict__ xs1,   // [N,32]
                               int N) {
    __shared__ float sW[512];
    for (int t = threadIdx.x; t < 512; t += blockDim.x) sW[t] = W1[t];
    __syncthreads();
    int i = blockIdx.x * blockDim.x + threadIdx.x;
    if (i >= N) return;

    float d = 1.0f / sqrtf(deg[i] + 1.0f);
    dis[i] = d;

    float xr[16];
#pragma unroll
    for (int k = 0; k < 4; ++k) {
        float4 v = ((const float4*)(x + (size_t)i * 16))[k];
        xr[4*k+0] = v.x; xr[4*k+1] = v.y; xr[4*k+2] = v.z; xr[4*k+3] = v.w;
    }
    float* outp = xs1 + (size_t)i * 32;
#pragma unroll
    for (int o = 0; o < 32; ++o) {
        float acc = 0.f;
#pragma unroll
        for (int k = 0; k < 16; ++k) acc += xr[k] * sW[o*16 + k];
        outp[o] = acc * d;
    }
}

// one wave per node, F=32: lanes = 32 features x 2 edge slots
__global__ void gather1_kernel(const int* __restrict__ ptr, const int2* __restrict__ rw,
                               const float* __restrict__ xs1, const float* __restrict__ dis,
                               const float* __restrict__ b1,
                               float* __restrict__ h, int N) {
    int wave = (blockIdx.x * blockDim.x + threadIdx.x) >> 6;
    int lane = threadIdx.x & 63;
    if (wave >= N) return;
    int f = lane & 31, slot = lane >> 5;
    int s0 = ptr[wave], s1 = ptr[wave + 1];

    float acc0 = 0.f, acc1 = 0.f;
    int e = s0 + slot;
    for (; e + 2 < s1; e += 4) {          // 2-way unroll (per-slot stride 2)
        int2 v0 = rw[e];
        int2 v1 = rw[e + 2];
        acc0 += __int_as_float(v0.y) * xs1[(size_t)v0.x * 32 + f];
        acc1 += __int_as_float(v1.y) * xs1[(size_t)v1.x * 32 + f];
    }
    if (e < s1) {
        int2 v0 = rw[e];
        acc0 += __int_as_float(v0.y) * xs1[(size_t)v0.x * 32 + f];
    }
    float acc = acc0 + acc1;
    acc += __shfl_xor(acc, 32);
    if (slot == 0) {
        float d = dis[wave];
        float self = xs1[(size_t)wave * 32 + f];
        h[(size_t)wave * 32 + f] = fmaxf(d * (acc + self) + b1[f], 0.f);
    }
}

// xs2 = (h @ W2^T) * dis   (W2: [16,32] row-major)
__global__ void epi1_kernel(const float* __restrict__ h,
                            const float* __restrict__ dis,
                            const float* __restrict__ W2,
                            float* __restrict__ xs2,  // [N,16]
                            int N) {
    __shared__ float sW[512];
    for (int t = threadIdx.x; t < 512; t += blockDim.x) sW[t] = W2[t];
    __syncthreads();
    int i = blockIdx.x * blockDim.x + threadIdx.x;
    if (i >= N) return;

    float hr[32];
#pragma unroll
    for (int k = 0; k < 8; ++k) {
        float4 v = ((const float4*)(h + (size_t)i * 32))[k];
        hr[4*k+0] = v.x; hr[4*k+1] = v.y; hr[4*k+2] = v.z; hr[4*k+3] = v.w;
    }
    float d = dis[i];
    float* outp = xs2 + (size_t)i * 16;
#pragma unroll
    for (int o = 0; o < 16; ++o) {
        float acc = 0.f;
#pragma unroll
        for (int k = 0; k < 32; ++k) acc += hr[k] * sW[o*32 + k];
        outp[o] = acc * d;
    }
}

// one wave per node, F=16: lanes = 16 features x 4 edge slots
__global__ void gather2_kernel(const int* __restrict__ ptr, const int2* __restrict__ rw,
                               const float* __restrict__ xs2, const float* __restrict__ dis,
                               const float* __restrict__ b2,
                               float* __restrict__ out, int N) {
    int wave = (blockIdx.x * blockDim.x + threadIdx.x) >> 6;
    int lane = threadIdx.x & 63;
    if (wave >= N) return;
    int f = lane & 15, slot = lane >> 4;
    int s0 = ptr[wave], s1 = ptr[wave + 1];

    float acc0 = 0.f, acc1 = 0.f;
    int e = s0 + slot;
    for (; e + 4 < s1; e += 8) {          // 2-way unroll (per-slot stride 4)
        int2 v0 = rw[e];
        int2 v1 = rw[e + 4];
        acc0 += __int_as_float(v0.y) * xs2[(size_t)v0.x * 16 + f];
        acc1 += __int_as_float(v1.y) * xs2[(size_t)v1.x * 16 + f];
    }
    if (e < s1) {
        int2 v0 = rw[e];
        acc0 += __int_as_float(v0.y) * xs2[(size_t)v0.x * 16 + f];
    }
    float acc = acc0 + acc1;
    acc += __shfl_xor(acc, 16);
    acc += __shfl_xor(acc, 32);
    if (slot == 0) {
        float d = dis[wave];
        out[(size_t)wave * 16 + f] = d * (acc + xs2[(size_t)wave * 16 + f]) + b2[f];
    }
}

extern "C" void kernel_launch(void* const* d_in, const int* in_sizes, int n_in,
                              void* d_out, int out_size, void* d_ws, size_t ws_size,
                              hipStream_t stream) {
    const float* x  = (const float*)d_in[0];
    const int*   ei = (const int*)d_in[1];   // [2, E] int32
    const float* ew = (const float*)d_in[2];
    const float* W1 = (const float*)d_in[3];
    const float* b1 = (const float*)d_in[4];
    const float* W2 = (const float*)d_in[5];
    const float* b2 = (const float*)d_in[6];
    float* out = (float*)d_out;

    const int N = in_sizes[0] / 16;
    const int E = in_sizes[2];
    const int* row = ei;
    const int* col = ei + E;

    // workspace layout (floats); rw first for 8B alignment
    float* ws   = (float*)d_ws;
    int2*  rw   = (int2*)ws;                         // E int2     (2E)
    float* xs1  = ws + (size_t)2 * E;                // N*32
    float* h    = xs1 + (size_t)N * 32;              // N*32
    float* xs2  = h   + (size_t)N * 32;              // N*16
    float* deg  = xs2 + (size_t)N * 16;              // N
    float* dis  = deg + N;                           // N
    int*   cnt  = (int*)(dis + N);                   // N
    int*   ptr  = cnt + N;                           // N+1
    int*   fill = ptr + N + 1;                       // N
    int*   bsum = fill + N;                          // <=512

    const int nb = (N + 255) / 256;

    hipMemsetAsync(cnt, 0, (size_t)N * 4, stream);
    hipMemsetAsync(deg, 0, (size_t)N * 4, stream);

    hist_kernel<<<(E + 255) / 256, 256, 0, stream>>>(col, ew, cnt, deg, E);
    scan1_kernel<<<nb, 256, 0, stream>>>(cnt, ptr, bsum, N);
    scan2_kernel<<<1, 512, 0, stream>>>(bsum, nb);
    scan3_kernel<<<(N + 256) / 256 + 1, 256, 0, stream>>>(ptr, bsum, fill, N, E);
    reorder_kernel<<<(E + 255) / 256, 256, 0, stream>>>(row, col, ew, fill, rw, E);

    dis_xw1_kernel<<<(N + 255) / 256, 256, 0, stream>>>(x, W1, deg, dis, xs1, N);

    gather1_kernel<<<(N + 3) / 4, 256, 0, stream>>>(ptr, rw, xs1, dis, b1, h, N);
    epi1_kernel<<<(N + 255) / 256, 256, 0, stream>>>(h, dis, W2, xs2, N);
    gather2_kernel<<<(N + 3) / 4, 256, 0, stream>>>(ptr, rw, xs2, dis, b2, out, N);
}